// Round 6
// baseline (67.030 us; speedup 1.0000x reference)
//
#include <hip/hip_runtime.h>
#include <math.h>

#define RR 8192
#define FF 4096
#define LL 2048
#define TPB 512            // 8 waves, wave-per-row, 8 rows/block
#define NBLK (RR / 8)      // 1024

// ws layout (floats): w1[FF] | w2[FF] | q | counter | pad | partials[NBLK*3]
#define WS_W1  0
#define WS_W2  FF
#define WS_Q   (2 * FF)
#define WS_CNT (2 * FF + 4)
#define WS_P   (2 * FF + 16)

// ---------------- kernel 1: prep (1 block) — verified ----------------
__global__ __launch_bounds__(1024) void prep(const float* __restrict__ in,
                                             const int* __restrict__ idx,
                                             const float* __restrict__ wts,
                                             float* __restrict__ ws) {
    __shared__ float w1s[FF];
    __shared__ float w2s[FF];
    __shared__ float qred[16];

    const int t = threadIdx.x, lane = t & 63, wv = t >> 6;

    for (int i = t; i < FF; i += 1024) { w1s[i] = 0.f; w2s[i] = 0.f; }
    __syncthreads();

    const float* lastrow = in + (size_t)(RR - 1) * FF;
    float qp = 0.f;
#pragma unroll
    for (int l = t; l < LL; l += 1024) {
        const int c = idx[l];
        qp += lastrow[c] * wts[3 * l + 0];
        atomicAdd(&w1s[c], wts[3 * l + 1]);
        atomicAdd(&w2s[c], wts[3 * l + 2]);
    }
    for (int o = 32; o > 0; o >>= 1) qp += __shfl_down(qp, o);
    if (lane == 0) qred[wv] = qp;
    __syncthreads();

    if (t < FF / 4) {
        *(float4*)(ws + WS_W1 + t * 4) = *(const float4*)&w1s[t * 4];
        *(float4*)(ws + WS_W2 + t * 4) = *(const float4*)&w2s[t * 4];
    }
    if (t == 0) {
        float q = 0.f;
#pragma unroll
        for (int i = 0; i < 16; ++i) q += qred[i];
        ws[WS_Q] = q;
        *((unsigned int*)(ws + WS_CNT)) = 0u;   // reset ticket every call
    }
}

// ---------------- kernel 2: batched wave-per-row GEMV(k,v) + ticket combine ----------------
__global__ __launch_bounds__(TPB) void gemv_combine(const float* __restrict__ in,
                                                    float* __restrict__ ws,
                                                    float* __restrict__ out) {
    __shared__ float w1s[FF];          // 16 KB
    __shared__ float w2s[FF];          // 16 KB
    __shared__ float kv[8][2];
    __shared__ int lastFlag;
    __shared__ float red[8], red2[8], red3[8], bc[1];

    const int t = threadIdx.x, lane = t & 63, wv = t >> 6;
    const int row = blockIdx.x * 8 + wv;
    const float* __restrict__ x = in + (size_t)row * FF;

    // ---- issue the wave's ENTIRE row as 16 concurrent global_load_dwordx4 ----
    float4 xa[16];
#pragma unroll
    for (int i = 0; i < 16; ++i) xa[i] = *(const float4*)(x + i * 256 + lane * 4);

    // ---- stage wsum into LDS (L2-hot, overlaps with the row loads above) ----
#pragma unroll
    for (int i = 0; i < 2; ++i) {
        const int c = (t + i * TPB) * 4;
        *(float4*)&w1s[c] = *(const float4*)(ws + WS_W1 + c);
        *(float4*)&w2s[c] = *(const float4*)(ws + WS_W2 + c);
    }
    __syncthreads();

    // ---- FMA pass against LDS weights ----
    float k = 0.f, v = 0.f;
#pragma unroll
    for (int i = 0; i < 16; ++i) {
        const int c = i * 256 + lane * 4;
        const float4 a1 = *(const float4*)&w1s[c];
        const float4 a2 = *(const float4*)&w2s[c];
        const float4 a = xa[i];
        k += a.x * a1.x + a.y * a1.y + a.z * a1.z + a.w * a1.w;
        v += a.x * a2.x + a.y * a2.y + a.z * a2.z + a.w * a2.w;
    }
    for (int o = 32; o > 0; o >>= 1) { k += __shfl_down(k, o); v += __shfl_down(v, o); }
    if (lane == 0) { kv[wv][0] = k; kv[wv][1] = v; }
    __syncthreads();

    if (t == 0) {
        const float q = ws[WS_Q];
        float m = -INFINITY;
#pragma unroll
        for (int r = 0; r < 8; ++r) m = fmaxf(m, q * kv[r][0]);
        float se = 0.f, sv = 0.f;
#pragma unroll
        for (int r = 0; r < 8; ++r) {
            const float e = expf(q * kv[r][0] - m);
            se += e;
            sv += e * kv[r][1];
        }
        float* p = ws + WS_P + blockIdx.x * 3;
        __hip_atomic_store(p + 0, m,  __ATOMIC_RELAXED, __HIP_MEMORY_SCOPE_AGENT);
        __hip_atomic_store(p + 1, se, __ATOMIC_RELAXED, __HIP_MEMORY_SCOPE_AGENT);
        __hip_atomic_store(p + 2, sv, __ATOMIC_RELAXED, __HIP_MEMORY_SCOPE_AGENT);
        __threadfence();
        const unsigned old = atomicAdd((unsigned int*)(ws + WS_CNT), 1u);
        lastFlag = (old == NBLK - 1) ? 1 : 0;
    }
    __syncthreads();
    if (!lastFlag) return;

    // ---- last-arriving block: merge 1024 partials -> sigmoid ----
    __threadfence();
    const float* __restrict__ P = ws + WS_P;
    float lm[NBLK / TPB], lse[NBLK / TPB], lsv[NBLK / TPB];
    float m = -INFINITY;
#pragma unroll
    for (int i = 0; i < NBLK / TPB; ++i) {
        const int b = t + i * TPB;
        lm[i]  = __hip_atomic_load(P + b * 3 + 0, __ATOMIC_RELAXED, __HIP_MEMORY_SCOPE_AGENT);
        lse[i] = __hip_atomic_load(P + b * 3 + 1, __ATOMIC_RELAXED, __HIP_MEMORY_SCOPE_AGENT);
        lsv[i] = __hip_atomic_load(P + b * 3 + 2, __ATOMIC_RELAXED, __HIP_MEMORY_SCOPE_AGENT);
        m = fmaxf(m, lm[i]);
    }
    for (int o = 32; o > 0; o >>= 1) m = fmaxf(m, __shfl_down(m, o));
    if (lane == 0) red[wv] = m;
    __syncthreads();
    if (t == 0) {
        float xx = red[0];
#pragma unroll
        for (int i = 1; i < 8; ++i) xx = fmaxf(xx, red[i]);
        bc[0] = xx;
    }
    __syncthreads();
    const float gm = bc[0];

    float se = 0.f, sv = 0.f;
#pragma unroll
    for (int i = 0; i < NBLK / TPB; ++i) {
        const float s = expf(lm[i] - gm);
        se += lse[i] * s;
        sv += lsv[i] * s;
    }
    for (int o = 32; o > 0; o >>= 1) { se += __shfl_down(se, o); sv += __shfl_down(sv, o); }
    if (lane == 0) { red2[wv] = se; red3[wv] = sv; }
    __syncthreads();
    if (t == 0) {
        float S = 0.f, V = 0.f;
#pragma unroll
        for (int i = 0; i < 8; ++i) { S += red2[i]; V += red3[i]; }
        out[0] = 1.0f / (1.0f + expf(-(V / S)));
    }
}

extern "C" void kernel_launch(void* const* d_in, const int* in_sizes, int n_in,
                              void* d_out, int out_size, void* d_ws, size_t ws_size,
                              hipStream_t stream) {
    const float* inputs = (const float*)d_in[0];
    const int*   idx    = (const int*)d_in[1];
    const float* wts    = (const float*)d_in[2];
    float* out = (float*)d_out;
    float* ws  = (float*)d_ws;

    prep<<<1, 1024, 0, stream>>>(inputs, idx, wts, ws);
    gemv_combine<<<NBLK, TPB, 0, stream>>>(inputs, ws, out);
}

// Round 7
// 48.945 us; speedup vs baseline: 1.3695x; 1.3695x over previous
//
#include <hip/hip_runtime.h>
#include <math.h>

#define RR 8192
#define FF 4096
#define LL 2048
#define NB2 512            // gemv blocks: 8 waves x 2 rows = 16 rows/block

// ws layout (floats): w1[FF] | w2[FF] | q | pad | partials[NB2*3]
#define WS_W1  0
#define WS_W2  FF
#define WS_Q   (2 * FF)
#define WS_P   (2 * FF + 16)

// ---------------- kernel 1: prep (1 block) — verified r3 ----------------
__global__ __launch_bounds__(1024) void prep(const float* __restrict__ in,
                                             const int* __restrict__ idx,
                                             const float* __restrict__ wts,
                                             float* __restrict__ ws) {
    __shared__ float w1s[FF];
    __shared__ float w2s[FF];
    __shared__ float qred[16];

    const int t = threadIdx.x, lane = t & 63, wv = t >> 6;

    for (int i = t; i < FF; i += 1024) { w1s[i] = 0.f; w2s[i] = 0.f; }
    __syncthreads();

    const float* lastrow = in + (size_t)(RR - 1) * FF;
    float qp = 0.f;
#pragma unroll
    for (int l = t; l < LL; l += 1024) {
        const int c = idx[l];
        qp += lastrow[c] * wts[3 * l + 0];
        atomicAdd(&w1s[c], wts[3 * l + 1]);
        atomicAdd(&w2s[c], wts[3 * l + 2]);
    }
    for (int o = 32; o > 0; o >>= 1) qp += __shfl_down(qp, o);
    if (lane == 0) qred[wv] = qp;
    __syncthreads();

    if (t < FF / 4) {
        *(float4*)(ws + WS_W1 + t * 4) = *(const float4*)&w1s[t * 4];
        *(float4*)(ws + WS_W2 + t * 4) = *(const float4*)&w2s[t * 4];
    }
    if (t == 0) {
        float q = 0.f;
#pragma unroll
        for (int i = 0; i < 16; ++i) q += qred[i];
        ws[WS_Q] = q;
    }
}

// ---------------- kernel 2: 2-rows/wave GEMV with depth-4 rolling prefetch ----------------
__global__ __launch_bounds__(512, 8) void gemv_kv(const float* __restrict__ in,
                                                  const float* __restrict__ ws,
                                                  float* __restrict__ partials) {
    const int t = threadIdx.x, lane = t & 63, wv = t >> 6;
    const int pair = blockIdx.x * 8 + wv;                 // 0..4095
    const float* __restrict__ x0 = in + (size_t)(pair * 2) * FF + lane * 4;
    const float* __restrict__ w1 = ws + WS_W1 + lane * 4;
    const float* __restrict__ w2 = ws + WS_W2 + lane * 4;

    // chunk j (0..31): first 16 chunks are row 2*pair, next 16 are row 2*pair+1
#define CH(j) (x0 + (((j) < 16) ? (j) * 256 : (FF + ((j) - 16) * 256)))

    float k0 = 0.f, v0 = 0.f, k1 = 0.f, v1 = 0.f;
    float4 xa[4];
#pragma unroll
    for (int j = 0; j < 4; ++j) xa[j] = *(const float4*)CH(j);

#pragma unroll
    for (int j = 0; j < 32; ++j) {
        const float4 cur = xa[j & 3];
        if (j + 4 < 32) xa[j & 3] = *(const float4*)CH(j + 4);
        const int wc = (j & 15) * 256;
        const float4 a1 = *(const float4*)(w1 + wc);
        const float4 a2 = *(const float4*)(w2 + wc);
        const float kd = cur.x * a1.x + cur.y * a1.y + cur.z * a1.z + cur.w * a1.w;
        const float vd = cur.x * a2.x + cur.y * a2.y + cur.z * a2.z + cur.w * a2.w;
        if (j < 16) { k0 += kd; v0 += vd; } else { k1 += kd; v1 += vd; }
    }
#undef CH

    for (int o = 32; o > 0; o >>= 1) {
        k0 += __shfl_down(k0, o); v0 += __shfl_down(v0, o);
        k1 += __shfl_down(k1, o); v1 += __shfl_down(v1, o);
    }

    __shared__ float kv[16][2];
    if (lane == 0) {
        kv[wv * 2 + 0][0] = k0; kv[wv * 2 + 0][1] = v0;
        kv[wv * 2 + 1][0] = k1; kv[wv * 2 + 1][1] = v1;
    }
    __syncthreads();

    if (t == 0) {
        const float q = ws[WS_Q];
        float m = -INFINITY;
#pragma unroll
        for (int r = 0; r < 16; ++r) m = fmaxf(m, q * kv[r][0]);
        float se = 0.f, sv = 0.f;
#pragma unroll
        for (int r = 0; r < 16; ++r) {
            const float e = expf(q * kv[r][0] - m);
            se += e;
            sv += e * kv[r][1];
        }
        partials[blockIdx.x * 3 + 0] = m;
        partials[blockIdx.x * 3 + 1] = se;
        partials[blockIdx.x * 3 + 2] = sv;
    }
}

// ---------------- kernel 3: merge 512 partials -> sigmoid ----------------
__global__ __launch_bounds__(512) void combine(const float* __restrict__ partials,
                                               float* __restrict__ out) {
    const int t = threadIdx.x, lane = t & 63, wv = t >> 6;
    const float lm  = partials[t * 3 + 0];
    const float lse = partials[t * 3 + 1];
    const float lsv = partials[t * 3 + 2];

    __shared__ float red[8], red2[8], red3[8], bc[1];
    float m = lm;
    for (int o = 32; o > 0; o >>= 1) m = fmaxf(m, __shfl_down(m, o));
    if (lane == 0) red[wv] = m;
    __syncthreads();
    if (t == 0) {
        float x = red[0];
#pragma unroll
        for (int i = 1; i < 8; ++i) x = fmaxf(x, red[i]);
        bc[0] = x;
    }
    __syncthreads();
    const float gm = bc[0];

    const float s = expf(lm - gm);
    float se = lse * s, sv = lsv * s;
    for (int o = 32; o > 0; o >>= 1) { se += __shfl_down(se, o); sv += __shfl_down(sv, o); }
    if (lane == 0) { red2[wv] = se; red3[wv] = sv; }
    __syncthreads();
    if (t == 0) {
        float S = 0.f, V = 0.f;
#pragma unroll
        for (int i = 0; i < 8; ++i) { S += red2[i]; V += red3[i]; }
        out[0] = 1.0f / (1.0f + expf(-(V / S)));
    }
}

extern "C" void kernel_launch(void* const* d_in, const int* in_sizes, int n_in,
                              void* d_out, int out_size, void* d_ws, size_t ws_size,
                              hipStream_t stream) {
    const float* inputs = (const float*)d_in[0];
    const int*   idx    = (const int*)d_in[1];
    const float* wts    = (const float*)d_in[2];
    float* out = (float*)d_out;
    float* ws  = (float*)d_ws;

    prep<<<1, 1024, 0, stream>>>(inputs, idx, wts, ws);
    gemv_kv<<<NB2, 512, 0, stream>>>(inputs, ws, ws + WS_P);
    combine<<<1, 512, 0, stream>>>(ws + WS_P, out);
}

// Round 8
// 38.784 us; speedup vs baseline: 1.7283x; 1.2620x over previous
//
#include <hip/hip_runtime.h>
#include <math.h>

#define RR 8192
#define FF 4096
#define LL 2048
#define NB 512             // gemv blocks: 8 waves x 2 rows = 16 rows/block

// ws layout (floats): w1[FF] | w2[FF] | q | pad | partials[NB*3]
#define WS_W1  0
#define WS_W2  FF
#define WS_Q   (2 * FF)
#define WS_P   (2 * FF + 16)

// ---------------- kernel 1: prep (2 blocks) ----------------
// block 0: w1 (k-weights) + q ;  block 1: w2 (v-weights)
__global__ __launch_bounds__(1024) void prep(const float* __restrict__ in,
                                             const int* __restrict__ idx,
                                             const float* __restrict__ wts,
                                             float* __restrict__ ws) {
    __shared__ float wsh[FF];
    __shared__ float qred[16];

    const int t = threadIdx.x, lane = t & 63, wv = t >> 6;
    const int b = blockIdx.x;

    for (int i = t; i < FF; i += 1024) wsh[i] = 0.f;
    __syncthreads();

    if (b == 0) {
        const float* lastrow = in + (size_t)(RR - 1) * FF;
        float qp = 0.f;
#pragma unroll
        for (int l = t; l < LL; l += 1024) {
            const int c = idx[l];
            qp += lastrow[c] * wts[3 * l + 0];
            atomicAdd(&wsh[c], wts[3 * l + 1]);
        }
        for (int o = 32; o > 0; o >>= 1) qp += __shfl_down(qp, o);
        if (lane == 0) qred[wv] = qp;
        __syncthreads();
        if (t < FF / 4)
            *(float4*)(ws + WS_W1 + t * 4) = *(const float4*)&wsh[t * 4];
        if (t == 0) {
            float q = 0.f;
#pragma unroll
            for (int i = 0; i < 16; ++i) q += qred[i];
            ws[WS_Q] = q;
        }
    } else {
#pragma unroll
        for (int l = t; l < LL; l += 1024) {
            atomicAdd(&wsh[idx[l]], wts[3 * l + 2]);
        }
        __syncthreads();
        if (t < FF / 4)
            *(float4*)(ws + WS_W2 + t * 4) = *(const float4*)&wsh[t * 4];
    }
}

// ---------------- kernel 2: 2-rows/wave GEMV(k,v), simple flat loop ----------------
__global__ __launch_bounds__(512) void gemv_kv(const float* __restrict__ in,
                                               const float* __restrict__ ws,
                                               float* __restrict__ partials) {
    const int t = threadIdx.x, lane = t & 63, wv = t >> 6;
    const int pair = blockIdx.x * 8 + wv;                  // 0..4095
    const float* __restrict__ xA = in + (size_t)(pair * 2) * FF;
    const float* __restrict__ xB = xA + FF;
    const float* __restrict__ w1 = ws + WS_W1;
    const float* __restrict__ w2 = ws + WS_W2;

    float k0 = 0.f, v0 = 0.f, k1 = 0.f, v1 = 0.f;
#pragma unroll
    for (int i = 0; i < 16; ++i) {
        const int c = i * 256 + lane * 4;
        const float4 xa = *(const float4*)(xA + c);
        const float4 xb = *(const float4*)(xB + c);
        const float4 a1 = *(const float4*)(w1 + c);
        const float4 a2 = *(const float4*)(w2 + c);
        k0 += xa.x * a1.x + xa.y * a1.y + xa.z * a1.z + xa.w * a1.w;
        v0 += xa.x * a2.x + xa.y * a2.y + xa.z * a2.z + xa.w * a2.w;
        k1 += xb.x * a1.x + xb.y * a1.y + xb.z * a1.z + xb.w * a1.w;
        v1 += xb.x * a2.x + xb.y * a2.y + xb.z * a2.z + xb.w * a2.w;
    }

    for (int o = 32; o > 0; o >>= 1) {
        k0 += __shfl_down(k0, o); v0 += __shfl_down(v0, o);
        k1 += __shfl_down(k1, o); v1 += __shfl_down(v1, o);
    }

    __shared__ float kv[16][2];
    if (lane == 0) {
        kv[wv * 2 + 0][0] = k0; kv[wv * 2 + 0][1] = v0;
        kv[wv * 2 + 1][0] = k1; kv[wv * 2 + 1][1] = v1;
    }
    __syncthreads();

    if (t == 0) {
        const float q = ws[WS_Q];
        float m = -INFINITY;
#pragma unroll
        for (int r = 0; r < 16; ++r) m = fmaxf(m, q * kv[r][0]);
        float se = 0.f, sv = 0.f;
#pragma unroll
        for (int r = 0; r < 16; ++r) {
            const float e = expf(q * kv[r][0] - m);
            se += e;
            sv += e * kv[r][1];
        }
        partials[blockIdx.x * 3 + 0] = m;
        partials[blockIdx.x * 3 + 1] = se;
        partials[blockIdx.x * 3 + 2] = sv;
    }
}

// ---------------- kernel 3: merge 512 partials -> sigmoid ----------------
__global__ __launch_bounds__(512) void combine(const float* __restrict__ partials,
                                               float* __restrict__ out) {
    const int t = threadIdx.x, lane = t & 63, wv = t >> 6;
    const float lm  = partials[t * 3 + 0];
    const float lse = partials[t * 3 + 1];
    const float lsv = partials[t * 3 + 2];

    __shared__ float red[8], red2[8], red3[8], bc[1];
    float m = lm;
    for (int o = 32; o > 0; o >>= 1) m = fmaxf(m, __shfl_down(m, o));
    if (lane == 0) red[wv] = m;
    __syncthreads();
    if (t == 0) {
        float x = red[0];
#pragma unroll
        for (int i = 1; i < 8; ++i) x = fmaxf(x, red[i]);
        bc[0] = x;
    }
    __syncthreads();
    const float gm = bc[0];

    const float s = expf(lm - gm);
    float se = lse * s, sv = lsv * s;
    for (int o = 32; o > 0; o >>= 1) { se += __shfl_down(se, o); sv += __shfl_down(sv, o); }
    if (lane == 0) { red2[wv] = se; red3[wv] = sv; }
    __syncthreads();
    if (t == 0) {
        float S = 0.f, V = 0.f;
#pragma unroll
        for (int i = 0; i < 8; ++i) { S += red2[i]; V += red3[i]; }
        out[0] = 1.0f / (1.0f + expf(-(V / S)));
    }
}

extern "C" void kernel_launch(void* const* d_in, const int* in_sizes, int n_in,
                              void* d_out, int out_size, void* d_ws, size_t ws_size,
                              hipStream_t stream) {
    const float* inputs = (const float*)d_in[0];
    const int*   idx    = (const int*)d_in[1];
    const float* wts    = (const float*)d_in[2];
    float* out = (float*)d_out;
    float* ws  = (float*)d_ws;

    prep<<<2, 1024, 0, stream>>>(inputs, idx, wts, ws);
    gemv_kv<<<NB, 512, 0, stream>>>(inputs, ws, ws + WS_P);
    combine<<<1, 512, 0, stream>>>(ws + WS_P, out);
}